// Round 1
// baseline (548.488 us; speedup 1.0000x reference)
//
#include <hip/hip_runtime.h>
#include <math.h>

// VQVAE codebook quantization: N=262144 rows, K=1024 codes, D=64.
// Outputs (flat fp32): Z[N], q_with_st[N*64], vq_loss, commitment_loss.
//
// Correctness strategy: bitwise-mimic the numpy fp32 reference:
//  - dot(x,c): sequential FMA over d=0..63 from 0 (BLAS sgemm k-loop order)
//  - x_sq / c_sq: numpy pairwise_sum structure for n=64 (8 accumulators,
//    ((r0+r1)+(r2+r3))+((r4+r5)+(r6+r7))), squares NOT fused (contract off)
//  - dist = (x_sq - 2*dot) + c_sq : exactly two rounded fp32 ops
//  - argmin: first index wins on exact ties (lex (val,idx) min)
//  - q_with_st = fl(x + fl(q - x))

static constexpr int NROWS = 262144;
static constexpr int KC    = 1024;
static constexpr int DIM   = 64;

// ---------------------------------------------------------------- c_sq
__global__ __launch_bounds__(256) void csq_kernel(const float* __restrict__ cb,
                                                  float* __restrict__ csq) {
#pragma clang fp contract(off)
    int c = blockIdx.x * blockDim.x + threadIdx.x;
    if (c >= KC) return;
    const float4* row = reinterpret_cast<const float4*>(cb + (size_t)c * DIM);
    float r[8];
#pragma unroll
    for (int g = 0; g < 8; ++g) {
        float4 v0 = row[2 * g];
        float4 v1 = row[2 * g + 1];
        float e[8] = {v0.x, v0.y, v0.z, v0.w, v1.x, v1.y, v1.z, v1.w};
#pragma unroll
        for (int j = 0; j < 8; ++j) {
            float sq = e[j] * e[j];     // rounded square (no fma)
            if (g == 0) r[j] = sq; else r[j] += sq;
        }
    }
    csq[c] = ((r[0] + r[1]) + (r[2] + r[3])) + ((r[4] + r[5]) + (r[6] + r[7]));
}

// ------------------------------------------------------- main GEMM+argmin
// block = 128 threads (2 waves), 128 rows/block, full K loop in 16 tiles of 64.
// wave tile 64 rows x 64 codes; thread tile 8x8.
__global__ __launch_bounds__(128) void vq_argmin_kernel(
        const float* __restrict__ x, const float* __restrict__ cb,
        const float* __restrict__ csq_g, float* __restrict__ zout) {
#pragma clang fp contract(off)
    __shared__ float At[64][128];   // [d][local_row]  32 KB
    __shared__ float Bt[64][64];    // [d][code_local] 16 KB
    __shared__ float xsq_l[128];
    __shared__ float csq_l[64];

    const int t = threadIdx.x;
    const int rowbase = blockIdx.x * 128;

    // ---- stage A transposed + per-row x_sq (numpy pairwise, no contraction)
    {
        const float4* xr = reinterpret_cast<const float4*>(x + (size_t)(rowbase + t) * DIM);
        float r[8];
#pragma unroll
        for (int g = 0; g < 8; ++g) {
            float4 v0 = xr[2 * g];
            float4 v1 = xr[2 * g + 1];
            float e[8] = {v0.x, v0.y, v0.z, v0.w, v1.x, v1.y, v1.z, v1.w};
#pragma unroll
            for (int j = 0; j < 8; ++j) {
                At[8 * g + j][t] = e[j];
                float sq = e[j] * e[j];
                if (g == 0) r[j] = sq; else r[j] += sq;
            }
        }
        xsq_l[t] = ((r[0] + r[1]) + (r[2] + r[3])) + ((r[4] + r[5]) + (r[6] + r[7]));
    }
    __syncthreads();

    const int lane = t & 63;
    const int w    = t >> 6;
    const int rg   = lane >> 3;   // row group 0..7
    const int cg   = lane & 7;    // code group 0..7
    const int lrow = w * 64 + rg * 8;

    float xsq[8];
#pragma unroll
    for (int i = 0; i < 8; ++i) xsq[i] = xsq_l[lrow + i];

    float minv[8];
    int   mini[8];
#pragma unroll
    for (int i = 0; i < 8; ++i) { minv[i] = INFINITY; mini[i] = 0; }

    for (int tile = 0; tile < 16; ++tile) {
        __syncthreads();   // previous tile's reads done before overwriting Bt
        {
            const int c  = t >> 1;
            const int d0 = (t & 1) * 32;
            const float4* cr = reinterpret_cast<const float4*>(
                cb + (size_t)(tile * 64 + c) * DIM + d0);
#pragma unroll
            for (int q = 0; q < 8; ++q) {
                float4 v = cr[q];
                int d = d0 + q * 4;
                Bt[d + 0][c] = v.x; Bt[d + 1][c] = v.y;
                Bt[d + 2][c] = v.z; Bt[d + 3][c] = v.w;
            }
            if (t < 64) csq_l[t] = csq_g[tile * 64 + t];
        }
        __syncthreads();

        float acc[8][8];
#pragma unroll
        for (int i = 0; i < 8; ++i)
#pragma unroll
            for (int j = 0; j < 8; ++j) acc[i][j] = 0.0f;

        // dot accumulation: d ascending, single accumulator, fused FMA per
        // step == BLAS sgemm microkernel rounding order.
#pragma unroll 8
        for (int d = 0; d < 64; ++d) {
            float4 a0 = *reinterpret_cast<const float4*>(&At[d][lrow]);
            float4 a1 = *reinterpret_cast<const float4*>(&At[d][lrow + 4]);
            float4 b0 = *reinterpret_cast<const float4*>(&Bt[d][cg * 8]);
            float4 b1 = *reinterpret_cast<const float4*>(&Bt[d][cg * 8 + 4]);
            float av[8] = {a0.x, a0.y, a0.z, a0.w, a1.x, a1.y, a1.z, a1.w};
            float bv[8] = {b0.x, b0.y, b0.z, b0.w, b1.x, b1.y, b1.z, b1.w};
#pragma unroll
            for (int i = 0; i < 8; ++i)
#pragma unroll
                for (int j = 0; j < 8; ++j)
                    acc[i][j] = __builtin_fmaf(av[i], bv[j], acc[i][j]);
        }

        // dist = (x_sq - 2*dot) + c_sq  : two rounded fp32 ops (2*dot exact).
#pragma unroll
        for (int i = 0; i < 8; ++i) {
#pragma unroll
            for (int j = 0; j < 8; ++j) {
                float dist = (xsq[i] - 2.0f * acc[i][j]) + csq_l[cg * 8 + j];
                int idx = tile * 64 + cg * 8 + j;
                // idx strictly increasing within a thread -> strict '<' is
                // exactly numpy first-min semantics thread-locally.
                if (dist < minv[i]) { minv[i] = dist; mini[i] = idx; }
            }
        }
    }

    // cross-lane reduce over the 8 code-groups (lanes differing in low 3 bits),
    // lexicographic (val, idx) min == global first-min.
#pragma unroll
    for (int s = 1; s < 8; s <<= 1) {
#pragma unroll
        for (int i = 0; i < 8; ++i) {
            float ov = __shfl_xor(minv[i], s, 64);
            int   oi = __shfl_xor(mini[i], s, 64);
            if (ov < minv[i] || (ov == minv[i] && oi < mini[i])) {
                minv[i] = ov; mini[i] = oi;
            }
        }
    }
    if (cg == 0) {
#pragma unroll
        for (int i = 0; i < 8; ++i)
            zout[rowbase + lrow + i] = (float)mini[i];
    }
}

// ------------------------------------------- gather + q_with_st + loss partials
__global__ __launch_bounds__(256) void epilogue_kernel(
        const float* __restrict__ x, const float* __restrict__ cb,
        const float* __restrict__ zf, float* __restrict__ qout,
        double* __restrict__ partial) {
#pragma clang fp contract(off)
    const int gid = blockIdx.x * 256 + threadIdx.x;
    const int row = gid >> 2;
    const int d0  = (gid & 3) * 16;
    const float4* xr = reinterpret_cast<const float4*>(x + (size_t)row * DIM + d0);
    const int z = (int)zf[row];
    const float4* qr = reinterpret_cast<const float4*>(cb + (size_t)z * DIM + d0);
    float4* op = reinterpret_cast<float4*>(qout + (size_t)row * DIM + d0);

    double lsum = 0.0;
#pragma unroll
    for (int q = 0; q < 4; ++q) {
        float4 xv = xr[q];
        float4 qv = qr[q];
        float da = qv.x - xv.x, db = qv.y - xv.y, dc = qv.z - xv.z, dd = qv.w - xv.w;
        float4 o;
        o.x = xv.x + da;  // fl(x + fl(q-x)) — mimic reference, don't simplify to q
        o.y = xv.y + db;
        o.z = xv.z + dc;
        o.w = xv.w + dd;
        op[q] = o;
        lsum += (double)(da * da) + (double)(db * db)
              + (double)(dc * dc) + (double)(dd * dd);
    }
#pragma unroll
    for (int s = 32; s >= 1; s >>= 1) lsum += __shfl_down(lsum, s, 64);
    __shared__ double wsum[4];
    const int lane = threadIdx.x & 63, wid = threadIdx.x >> 6;
    if (lane == 0) wsum[wid] = lsum;
    __syncthreads();
    if (threadIdx.x == 0)
        partial[blockIdx.x] = (wsum[0] + wsum[1]) + (wsum[2] + wsum[3]);
}

// ---------------------------------------------------------------- finalize
__global__ void finalize_kernel(const double* __restrict__ partial,
                                float* __restrict__ losses) {
    double s = 0.0;
    int lane = threadIdx.x;  // 64 threads, deterministic fixed-order reduce
    for (int i = lane; i < 4096; i += 64) s += partial[i];
#pragma unroll
    for (int sh = 32; sh >= 1; sh >>= 1) s += __shfl_down(s, sh, 64);
    if (lane == 0) {
        float v = (float)(s / 16777216.0);
        losses[0] = v;   // vq_loss
        losses[1] = v;   // commitment_loss (numerically identical)
    }
}

extern "C" void kernel_launch(void* const* d_in, const int* in_sizes, int n_in,
                              void* d_out, int out_size, void* d_ws, size_t ws_size,
                              hipStream_t stream) {
    const float* x  = (const float*)d_in[0];
    const float* cb = (const float*)d_in[1];
    float* out    = (float*)d_out;
    float* zout   = out;                              // [N]
    float* qout   = out + NROWS;                      // [N*64]
    float* losses = out + NROWS + (size_t)NROWS * DIM; // [2]

    float*  csq     = (float*)d_ws;                          // 1024 floats
    double* partial = (double*)((char*)d_ws + 4096);         // 4096 doubles

    csq_kernel<<<4, 256, 0, stream>>>(cb, csq);
    vq_argmin_kernel<<<NROWS / 128, 128, 0, stream>>>(x, cb, csq, zout);
    epilogue_kernel<<<(NROWS * 4) / 256, 256, 0, stream>>>(x, cb, zout, qout, partial);
    finalize_kernel<<<1, 64, 0, stream>>>(partial, losses);
}

// Round 3
// 444.987 us; speedup vs baseline: 1.2326x; 1.2326x over previous
//
#include <hip/hip_runtime.h>
#include <math.h>

// VQVAE: N=262144, K=1024, D=64. Outputs flat fp32: Z[N], q_with_st[N*64], 2 losses.
// bf16-split MFMA distance pass (xh*ch + xh*cl + xl*ch), per-row error-certified
// argmin; ambiguous rows (top-2 gap <= T) exactly rescored with the bitwise
// reference-matching fp32 formula (verified absmax 0.0 in round 1).

static constexpr int NROWS = 262144;
static constexpr int KC    = 1024;
static constexpr int DIM   = 64;
static constexpr int CAP   = 65536;

// d_ws layout (bytes)
static constexpr size_t CSQ_OFF    = 0;          // 1024 f32
static constexpr size_t CSPLIT_OFF = 4096;       // 8 chunks x 16 slots x 128 codes x 16B = 256 KB
static constexpr size_t CTR_OFF    = 266240;     // 1 int
static constexpr size_t LIST_OFF   = 266244;     // CAP ints
static constexpr size_t PART_OFF   = 528392;     // 4096 doubles

typedef __attribute__((ext_vector_type(8)))  short   short8;
typedef __attribute__((ext_vector_type(8)))  unsigned short ushort8;
typedef __attribute__((ext_vector_type(16))) float   f32x16;

static __device__ __forceinline__ unsigned short bf16rn(float f) {
    unsigned u = __float_as_uint(f);
    u += 0x7fffu + ((u >> 16) & 1u);      // round-nearest-even to bf16
    return (unsigned short)(u >> 16);
}

// ---------------------------------------------------------------- c_sq (exact, ref-matching)
__global__ __launch_bounds__(256) void csq_kernel(const float* __restrict__ cb,
                                                  float* __restrict__ csq) {
#pragma clang fp contract(off)
    int c = blockIdx.x * blockDim.x + threadIdx.x;
    if (c >= KC) return;
    const float4* row = reinterpret_cast<const float4*>(cb + (size_t)c * DIM);
    float r[8];
#pragma unroll
    for (int g = 0; g < 8; ++g) {
        float4 v0 = row[2 * g];
        float4 v1 = row[2 * g + 1];
        float e[8] = {v0.x, v0.y, v0.z, v0.w, v1.x, v1.y, v1.z, v1.w};
#pragma unroll
        for (int j = 0; j < 8; ++j) {
            float sq = e[j] * e[j];
            if (g == 0) r[j] = sq; else r[j] += sq;
        }
    }
    csq[c] = ((r[0] + r[1]) + (r[2] + r[3])) + ((r[4] + r[5]) + (r[6] + r[7]));
}

// ---------------------------------------------------------------- codebook hi/lo split
// Global layout: ushort index = chunk*16384 + slot*1024 + code_l*8 + e
//   chunk = c>>7, code_l = c&127; hi of d: slot = d>>3; lo of d: slot = 8+(d>>3); e = d&7.
// This makes the per-chunk copy linear and the MFMA B-read lane-contiguous 16B.
__global__ __launch_bounds__(256) void csplit_kernel(const float* __restrict__ cb,
                                                     unsigned short* __restrict__ cs) {
    int gid = blockIdx.x * 256 + threadIdx.x;          // 4096 threads
    int c   = gid >> 2;
    int seg = (gid & 3) * 16;                          // d base: 0/16/32/48
    int chk = c >> 7, c_l = c & 127;
    const float4* src = reinterpret_cast<const float4*>(cb + (size_t)c * DIM + seg);
    ushort8 hi0, hi1, lo0, lo1;
#pragma unroll
    for (int q = 0; q < 4; ++q) {
        float4 v = src[q];
        float e[4] = {v.x, v.y, v.z, v.w};
#pragma unroll
        for (int k = 0; k < 4; ++k) {
            unsigned short hb = bf16rn(e[k]);
            float fh = __uint_as_float((unsigned)hb << 16);
            unsigned short lb = bf16rn(e[k] - fh);
            int idx = q * 4 + k;
            if (idx < 8) { hi0[idx] = hb; lo0[idx] = lb; }
            else         { hi1[idx - 8] = hb; lo1[idx - 8] = lb; }
        }
    }
    int s0 = seg >> 3;                                  // 0,2,4,6
    unsigned short* base = cs + (size_t)chk * 16384 + (size_t)c_l * 8;
    *reinterpret_cast<ushort8*>(base + (s0    ) * 1024) = hi0;
    *reinterpret_cast<ushort8*>(base + (s0 + 1) * 1024) = hi1;
    *reinterpret_cast<ushort8*>(base + (8 + s0) * 1024) = lo0;
    *reinterpret_cast<ushort8*>(base + (9 + s0) * 1024) = lo1;
}

// ---------------------------------------------------------------- MFMA distance + argmin
// 256 thr = 4 waves; wave owns 64 rows (2 M-tiles of 32); block = 256 rows.
// 1024 codes in 8 LDS chunks of 128. Per code-tile: 8 ds_read_b128, 24 MFMA.
__global__ __launch_bounds__(256) void vq_mfma_kernel(
        const float* __restrict__ x, const unsigned short* __restrict__ csplit,
        const float* __restrict__ csq_g, float* __restrict__ zout,
        int* __restrict__ counter, int* __restrict__ list) {
    __shared__ unsigned short bbuf[16384];   // 32 KB: [slot16][code128][8 ushort]
    __shared__ float csq_s[128];
    __shared__ float sumabs_s[4][64];

    const int tid   = threadIdx.x;
    const int w     = tid >> 6;
    const int lane  = tid & 63;
    const int h     = lane >> 5;          // k-half
    const int c_off = lane & 31;
    const int rowbase = blockIdx.x * 256 + w * 64;

    // A fragments: 2 row-tiles, split fp32 -> bf16 hi/lo in registers.
    // frag [R][j] element e  <->  x[rowbase+R*32+c_off][j*16 + h*8 + e]
    short8 ah[2][4], al[2][4];
#pragma unroll
    for (int R = 0; R < 2; ++R) {
        const float* xrow = x + (size_t)(rowbase + R * 32 + c_off) * DIM;
        float sa = 0.0f;
#pragma unroll
        for (int j = 0; j < 4; ++j) {
            float4 p0 = *reinterpret_cast<const float4*>(xrow + j * 16 + h * 8);
            float4 p1 = *reinterpret_cast<const float4*>(xrow + j * 16 + h * 8 + 4);
            float v[8] = {p0.x, p0.y, p0.z, p0.w, p1.x, p1.y, p1.z, p1.w};
#pragma unroll
            for (int e = 0; e < 8; ++e) {
                float f = v[e];
                sa += fabsf(f);
                unsigned short hb = bf16rn(f);
                float fh = __uint_as_float((unsigned)hb << 16);
                unsigned short lb = bf16rn(f - fh);
                ah[R][j][e] = (short)hb;
                al[R][j][e] = (short)lb;
            }
        }
        sa += __shfl_xor(sa, 32, 64);             // complementary d-half, same row
        if (h == 0) sumabs_s[w][R * 32 + c_off] = sa;
    }

    float m1[2][16], m2[2][16];
    int   i1[2][16];
#pragma unroll
    for (int R = 0; R < 2; ++R)
#pragma unroll
        for (int r = 0; r < 16; ++r) { m1[R][r] = INFINITY; m2[R][r] = INFINITY; i1[R][r] = 0; }

    for (int chk = 0; chk < 8; ++chk) {
        __syncthreads();                       // protect previous chunk reads
        {   // stage full 32 KB chunk, linear copy (2048 short8, 8 per thread)
            const short8* src = reinterpret_cast<const short8*>(
                (const char*)csplit + (size_t)chk * 32768);
            short8* dst = reinterpret_cast<short8*>(bbuf);
#pragma unroll
            for (int it = 0; it < 8; ++it) {
                int idx = it * 256 + tid;
                dst[idx] = src[idx];
            }
            if (tid < 128) csq_s[tid] = csq_g[chk * 128 + tid];
        }
        __syncthreads();

#pragma unroll
        for (int t = 0; t < 4; ++t) {          // 4 code-tiles of 32
            const int code_l = t * 32 + c_off;
            const char* bp = (const char*)bbuf + code_l * 16;
            f32x16 acc0 = {}, acc1 = {};
#pragma unroll
            for (int j = 0; j < 4; ++j) {
                short8 bch = *reinterpret_cast<const short8*>(bp + (2 * j + h) * 2048);
                short8 bcl = *reinterpret_cast<const short8*>(bp + (8 + 2 * j + h) * 2048);
                acc0 = __builtin_amdgcn_mfma_f32_32x32x16_bf16(ah[0][j], bch, acc0, 0, 0, 0);
                acc1 = __builtin_amdgcn_mfma_f32_32x32x16_bf16(ah[1][j], bch, acc1, 0, 0, 0);
                acc0 = __builtin_amdgcn_mfma_f32_32x32x16_bf16(al[0][j], bch, acc0, 0, 0, 0);
                acc1 = __builtin_amdgcn_mfma_f32_32x32x16_bf16(al[1][j], bch, acc1, 0, 0, 0);
                acc0 = __builtin_amdgcn_mfma_f32_32x32x16_bf16(ah[0][j], bcl, acc0, 0, 0, 0);
                acc1 = __builtin_amdgcn_mfma_f32_32x32x16_bf16(ah[1][j], bcl, acc1, 0, 0, 0);
            }
            float cs    = csq_s[code_l];
            int   codeg = chk * 128 + code_l;
#pragma unroll
            for (int r = 0; r < 16; ++r) {
                float sc0 = fmaf(-2.0f, acc0[r], cs);
                m2[0][r] = fminf(m2[0][r], fmaxf(sc0, m1[0][r]));
                if (sc0 < m1[0][r]) { m1[0][r] = sc0; i1[0][r] = codeg; }
                float sc1 = fmaf(-2.0f, acc1[r], cs);
                m2[1][r] = fminf(m2[1][r], fmaxf(sc1, m1[1][r]));
                if (sc1 < m1[1][r]) { m1[1][r] = sc1; i1[1][r] = codeg; }
            }
        }
    }

    // cross-lane reduce over the 32 code-slots (bits 0..4), lex (val,idx) min
#pragma unroll
    for (int m = 1; m <= 16; m <<= 1) {
#pragma unroll
        for (int R = 0; R < 2; ++R)
#pragma unroll
            for (int r = 0; r < 16; ++r) {
                float o1 = __shfl_xor(m1[R][r], m, 64);
                int   oi = __shfl_xor(i1[R][r], m, 64);
                float o2 = __shfl_xor(m2[R][r], m, 64);
                float nm2 = fminf(fminf(m2[R][r], o2), fmaxf(m1[R][r], o1));
                bool take = (o1 < m1[R][r]) || (o1 == m1[R][r] && oi < i1[R][r]);
                if (take) { m1[R][r] = o1; i1[R][r] = oi; }
                m2[R][r] = nm2;
            }
    }

    if (c_off == 0) {
#pragma unroll
        for (int R = 0; R < 2; ++R)
#pragma unroll
            for (int r = 0; r < 16; ++r) {
                int rw   = R * 32 + (r & 3) + 8 * (r >> 2) + 4 * h;   // D-layout row
                int grow = rowbase + rw;
                zout[grow] = (float)i1[R][r];
                float T = 1e-4f * sumabs_s[w][rw] + 2e-4f;
                if (m2[R][r] - m1[R][r] <= T) {
                    int id = atomicAdd(counter, 1);
                    if (id < CAP) list[id] = grow;
                }
            }
    }
}

// ---------------------------------------------------------------- exact rescore (bitwise ref)
__global__ __launch_bounds__(256) void rescore_kernel(
        const float* __restrict__ x, const float* __restrict__ cb,
        const float* __restrict__ csq, const int* __restrict__ counter,
        const int* __restrict__ list, float* __restrict__ zout) {
#pragma clang fp contract(off)
    const int wglobal = blockIdx.x * 4 + (threadIdx.x >> 6);
    const int lane    = threadIdx.x & 63;
    int cnt = *counter; if (cnt > CAP) cnt = CAP;

    for (int i = wglobal; i < cnt; i += 1024) {
        const int row = list[i];
        const float4* xr = reinterpret_cast<const float4*>(x + (size_t)row * DIM);
        float xv[64];
#pragma unroll
        for (int q = 0; q < 16; ++q) {
            float4 v = xr[q];
            xv[q * 4 + 0] = v.x; xv[q * 4 + 1] = v.y;
            xv[q * 4 + 2] = v.z; xv[q * 4 + 3] = v.w;
        }
        float r8[8];
#pragma unroll
        for (int g = 0; g < 8; ++g)
#pragma unroll
            for (int j = 0; j < 8; ++j) {
                float sq = xv[8 * g + j] * xv[8 * g + j];
                if (g == 0) r8[j] = sq; else r8[j] += sq;
            }
        float xsq = ((r8[0] + r8[1]) + (r8[2] + r8[3])) + ((r8[4] + r8[5]) + (r8[6] + r8[7]));

        float bm = INFINITY; int bi = 0;
        for (int cc = 0; cc < 16; ++cc) {
            int c = lane * 16 + cc;
            const float4* cr = reinterpret_cast<const float4*>(cb + (size_t)c * DIM);
            float dot = 0.0f;
#pragma unroll
            for (int q = 0; q < 16; ++q) {
                float4 v = cr[q];
                dot = __builtin_fmaf(v.x, xv[q * 4 + 0], dot);
                dot = __builtin_fmaf(v.y, xv[q * 4 + 1], dot);
                dot = __builtin_fmaf(v.z, xv[q * 4 + 2], dot);
                dot = __builtin_fmaf(v.w, xv[q * 4 + 3], dot);
            }
            float dist = (xsq - 2.0f * dot) + csq[c];
            if (dist < bm) { bm = dist; bi = c; }      // in-lane codes ascending
        }
#pragma unroll
        for (int m = 1; m <= 32; m <<= 1) {
            float ov = __shfl_xor(bm, m, 64);
            int   oi = __shfl_xor(bi, m, 64);
            if (ov < bm || (ov == bm && oi < bi)) { bm = ov; bi = oi; }
        }
        if (lane == 0) zout[row] = (float)bi;
    }
}

// ---------------------------------------------------------------- gather + ST out + losses
__global__ __launch_bounds__(256) void epilogue_kernel(
        const float* __restrict__ x, const float* __restrict__ cb,
        const float* __restrict__ zf, float* __restrict__ qout,
        double* __restrict__ partial) {
#pragma clang fp contract(off)
    const int gid = blockIdx.x * 256 + threadIdx.x;
    const int row = gid >> 2;
    const int d0  = (gid & 3) * 16;
    const float4* xr = reinterpret_cast<const float4*>(x + (size_t)row * DIM + d0);
    const int z = (int)zf[row];
    const float4* qr = reinterpret_cast<const float4*>(cb + (size_t)z * DIM + d0);
    float4* op = reinterpret_cast<float4*>(qout + (size_t)row * DIM + d0);

    double lsum = 0.0;
#pragma unroll
    for (int q = 0; q < 4; ++q) {
        float4 xv = xr[q];
        float4 qv = qr[q];
        float da = qv.x - xv.x, db = qv.y - xv.y, dc = qv.z - xv.z, dd = qv.w - xv.w;
        float4 o;
        o.x = xv.x + da; o.y = xv.y + db; o.z = xv.z + dc; o.w = xv.w + dd;
        op[q] = o;
        lsum += (double)(da * da) + (double)(db * db)
              + (double)(dc * dc) + (double)(dd * dd);
    }
#pragma unroll
    for (int s = 32; s >= 1; s >>= 1) lsum += __shfl_down(lsum, s, 64);
    __shared__ double wsum[4];
    const int lane = threadIdx.x & 63, wid = threadIdx.x >> 6;
    if (lane == 0) wsum[wid] = lsum;
    __syncthreads();
    if (threadIdx.x == 0)
        partial[blockIdx.x] = (wsum[0] + wsum[1]) + (wsum[2] + wsum[3]);
}

__global__ void finalize_kernel(const double* __restrict__ partial,
                                float* __restrict__ losses) {
    double s = 0.0;
    int lane = threadIdx.x;
    for (int i = lane; i < 4096; i += 64) s += partial[i];
#pragma unroll
    for (int sh = 32; sh >= 1; sh >>= 1) s += __shfl_down(s, sh, 64);
    if (lane == 0) {
        float v = (float)(s / 16777216.0);
        losses[0] = v;
        losses[1] = v;
    }
}

extern "C" void kernel_launch(void* const* d_in, const int* in_sizes, int n_in,
                              void* d_out, int out_size, void* d_ws, size_t ws_size,
                              hipStream_t stream) {
    const float* x  = (const float*)d_in[0];
    const float* cb = (const float*)d_in[1];
    float* out    = (float*)d_out;
    float* zout   = out;
    float* qout   = out + NROWS;
    float* losses = out + NROWS + (size_t)NROWS * DIM;

    float*          csq     = (float*)((char*)d_ws + CSQ_OFF);
    unsigned short* csplit  = (unsigned short*)((char*)d_ws + CSPLIT_OFF);
    int*            counter = (int*)((char*)d_ws + CTR_OFF);
    int*            list    = (int*)((char*)d_ws + LIST_OFF);
    double*         partial = (double*)((char*)d_ws + PART_OFF);

    hipMemsetAsync(counter, 0, sizeof(int), stream);
    csq_kernel<<<4, 256, 0, stream>>>(cb, csq);
    csplit_kernel<<<16, 256, 0, stream>>>(cb, csplit);
    vq_mfma_kernel<<<NROWS / 256, 256, 0, stream>>>(x, csplit, csq, zout, counter, list);
    rescore_kernel<<<256, 256, 0, stream>>>(x, cb, csq, counter, list, zout);
    epilogue_kernel<<<(NROWS * 4) / 256, 256, 0, stream>>>(x, cb, zout, qout, partial);
    finalize_kernel<<<1, 64, 0, stream>>>(partial, losses);
}

// Round 4
// 377.463 us; speedup vs baseline: 1.4531x; 1.1789x over previous
//
#include <hip/hip_runtime.h>
#include <math.h>
#include <limits.h>

// VQVAE: N=262144, K=1024, D=64. Outputs flat fp32: Z[N], q_with_st[N*64], 2 losses.
// bf16-split MFMA distances with SWAPPED operands (D[code][row]; lane = x-row,
// regs = codes) so argmin state is per-lane scalar packed int keys.
// Ambiguous rows (top-2 gap <= T) exactly rescored with the bitwise
// reference-matching fp32 formula (verified absmax 0.0 in rounds 1/3).

static constexpr int NROWS = 262144;
static constexpr int KC    = 1024;
static constexpr int DIM   = 64;
static constexpr int CAP   = 65536;

// d_ws layout (bytes)
static constexpr size_t CSQ_OFF    = 0;          // 1024 f32
static constexpr size_t CSPRE_OFF  = 4096;       // 1024 f32 (= -csq/2)
static constexpr size_t CSPLIT_OFF = 8192;       // 16 chunks x 16 slots x 64 codes x 16B = 256 KB
static constexpr size_t CTR_OFF    = 270336;     // 1 int
static constexpr size_t LIST_OFF   = 270340;     // CAP ints
static constexpr size_t PART_OFF   = 532488;     // 4096 doubles

typedef __attribute__((ext_vector_type(8)))  short   short8;
typedef __attribute__((ext_vector_type(8)))  unsigned short ushort8;
typedef __attribute__((ext_vector_type(16))) float   f32x16;

static __device__ __forceinline__ unsigned short bf16rn(float f) {
    unsigned u = __float_as_uint(f);
    u += 0x7fffu + ((u >> 16) & 1u);      // round-nearest-even to bf16
    return (unsigned short)(u >> 16);
}
static __device__ __forceinline__ int imin(int a, int b) { return a < b ? a : b; }
static __device__ __forceinline__ int imax(int a, int b) { return a > b ? a : b; }

// ------------------------------------------------ prep: csq (exact), cs_pre, hi/lo split
// csplit ushort index = chk*8192 + slot*512 + c_l*8 + e ; chk=c>>6, c_l=c&63
// slot for hi of dim d: d>>3 ; for lo: 8+(d>>3) ; e = d&7.
__global__ __launch_bounds__(64) void prep_kernel(const float* __restrict__ cb,
                                                  float* __restrict__ csq,
                                                  float* __restrict__ cspre,
                                                  unsigned short* __restrict__ cs) {
#pragma clang fp contract(off)
    const int c = blockIdx.x * 64 + threadIdx.x;
    const float4* row = reinterpret_cast<const float4*>(cb + (size_t)c * DIM);
    float e[64];
#pragma unroll
    for (int q = 0; q < 16; ++q) {
        float4 v = row[q];
        e[q * 4 + 0] = v.x; e[q * 4 + 1] = v.y;
        e[q * 4 + 2] = v.z; e[q * 4 + 3] = v.w;
    }
    float r[8];
#pragma unroll
    for (int g = 0; g < 8; ++g)
#pragma unroll
        for (int j = 0; j < 8; ++j) {
            float sq = e[8 * g + j] * e[8 * g + j];     // rounded square (no fma)
            if (g == 0) r[j] = sq; else r[j] += sq;
        }
    float s = ((r[0] + r[1]) + (r[2] + r[3])) + ((r[4] + r[5]) + (r[6] + r[7]));
    csq[c]   = s;
    cspre[c] = -0.5f * s;                               // exact (x0.5)

    const int chk = c >> 6, c_l = c & 63;
    unsigned short* base = cs + (size_t)chk * 8192 + (size_t)c_l * 8;
#pragma unroll
    for (int g = 0; g < 8; ++g) {
        ushort8 hi, lo;
#pragma unroll
        for (int j = 0; j < 8; ++j) {
            float f = e[8 * g + j];
            unsigned short hb = bf16rn(f);
            float fh = __uint_as_float((unsigned)hb << 16);
            hi[j] = hb;
            lo[j] = bf16rn(f - fh);
        }
        *reinterpret_cast<ushort8*>(base + g * 512)       = hi;
        *reinterpret_cast<ushort8*>(base + (8 + g) * 512) = lo;
    }
}

// ------------------------------------------------ MFMA distance + packed-key argmin
// 256 thr = 4 waves; wave owns 64 rows (2 accs of 32). 16 chunks of 64 codes,
// double-buffered LDS staged via global_load_lds, 1 barrier/chunk.
#define STAGE(buf_, chk_) do {                                                          \
    const char* _s = (const char*)csplit + (size_t)(chk_) * 16384                       \
                     + (size_t)(w * 4) * 1024 + (size_t)lane * 16;                      \
    char* _d = (char*)(&bbuf[buf_][0]) + (size_t)(w * 4) * 1024;                        \
    _Pragma("unroll")                                                                   \
    for (int _it = 0; _it < 4; ++_it)                                                   \
        __builtin_amdgcn_global_load_lds(                                               \
            (const __attribute__((address_space(1))) unsigned int*)(_s + _it * 1024),   \
            (__attribute__((address_space(3))) unsigned int*)(_d + _it * 1024),         \
            16, 0, 0);                                                                  \
} while (0)

__global__ __launch_bounds__(256, 3) void vq_mfma_kernel(
        const float* __restrict__ x, const unsigned short* __restrict__ csplit,
        const float* __restrict__ cspre_g, float* __restrict__ zout,
        int* __restrict__ counter, int* __restrict__ list) {
    __shared__ unsigned short bbuf[2][8192];   // 2 x 16 KB
    __shared__ float cspre_s[1024];            // 4 KB

    const int tid  = threadIdx.x;
    const int w    = tid >> 6;
    const int lane = tid & 63;
    const int h    = lane >> 5;
    const int cl5  = lane & 31;
    const int rowbase = blockIdx.x * 256 + w * 64;

    STAGE(0, 0);                               // chunk 0 in flight

    {   // cs_pre -> LDS (256 thr x 4 floats)
        float4 v = reinterpret_cast<const float4*>(cspre_g)[tid];
        reinterpret_cast<float4*>(cspre_s)[tid] = v;
    }

    // x fragments (B-operand): col = lane&31 = row; k = h*8 + e per 16-step j.
    short8 xh[2][4], xl[2][4];
    float sa[2];
#pragma unroll
    for (int R = 0; R < 2; ++R) {
        const float* xrow = x + (size_t)(rowbase + R * 32 + cl5) * DIM;
        float s = 0.0f;
#pragma unroll
        for (int j = 0; j < 4; ++j) {
            float4 p0 = *reinterpret_cast<const float4*>(xrow + j * 16 + h * 8);
            float4 p1 = *reinterpret_cast<const float4*>(xrow + j * 16 + h * 8 + 4);
            float v[8] = {p0.x, p0.y, p0.z, p0.w, p1.x, p1.y, p1.z, p1.w};
#pragma unroll
            for (int e = 0; e < 8; ++e) {
                float f = v[e];
                s += fabsf(f);
                unsigned short hb = bf16rn(f);
                float fh = __uint_as_float((unsigned)hb << 16);
                xh[R][j][e] = (short)hb;
                xl[R][j][e] = (short)bf16rn(f - fh);
            }
        }
        s += __shfl_xor(s, 32, 64);            // complementary d-half, same row
        sa[R] = s;
    }
    __syncthreads();                           // chunk0 + cspre ready

    int k1[2] = {INT_MAX, INT_MAX};
    int k2[2] = {INT_MAX, INT_MAX};

    for (int chk = 0; chk < 16; ++chk) {
        const int cur = chk & 1;
        if (chk < 15) STAGE(cur ^ 1, chk + 1);
        const char* bb = (const char*)(&bbuf[cur][0]);
#pragma unroll
        for (int t = 0; t < 2; ++t) {
            const int cbase = chk * 64 + t * 32 + 4 * h;
            const float* cp = &cspre_s[cbase];             // broadcast reads
            float4 cg0 = *reinterpret_cast<const float4*>(cp);
            float4 cg1 = *reinterpret_cast<const float4*>(cp + 8);
            float4 cg2 = *reinterpret_cast<const float4*>(cp + 16);
            float4 cg3 = *reinterpret_cast<const float4*>(cp + 24);
            f32x16 a0;
            a0[0] = cg0.x; a0[1] = cg0.y; a0[2]  = cg0.z; a0[3]  = cg0.w;
            a0[4] = cg1.x; a0[5] = cg1.y; a0[6]  = cg1.z; a0[7]  = cg1.w;
            a0[8] = cg2.x; a0[9] = cg2.y; a0[10] = cg2.z; a0[11] = cg2.w;
            a0[12] = cg3.x; a0[13] = cg3.y; a0[14] = cg3.z; a0[15] = cg3.w;
            f32x16 a1 = a0;                                // acc init = -csq/2
            const char* bp = bb + (size_t)(t * 32 + cl5) * 16;
#pragma unroll
            for (int j = 0; j < 4; ++j) {                  // A-operand: codes
                short8 bch = *reinterpret_cast<const short8*>(bp + (2 * j + h) * 1024);
                short8 bcl = *reinterpret_cast<const short8*>(bp + (8 + 2 * j + h) * 1024);
                a0 = __builtin_amdgcn_mfma_f32_32x32x16_bf16(bch, xh[0][j], a0, 0, 0, 0);
                a1 = __builtin_amdgcn_mfma_f32_32x32x16_bf16(bch, xh[1][j], a1, 0, 0, 0);
                a0 = __builtin_amdgcn_mfma_f32_32x32x16_bf16(bch, xl[0][j], a0, 0, 0, 0);
                a1 = __builtin_amdgcn_mfma_f32_32x32x16_bf16(bch, xl[1][j], a1, 0, 0, 0);
                a0 = __builtin_amdgcn_mfma_f32_32x32x16_bf16(bcl, xh[0][j], a0, 0, 0, 0);
                a1 = __builtin_amdgcn_mfma_f32_32x32x16_bf16(bcl, xh[1][j], a1, 0, 0, 0);
            }
            // acc = dot - csq/2 ; key = (trunc(-131072*acc)<<10) | code
#pragma unroll
            for (int r = 0; r < 16; ++r) {
                const int idx = (r & 3) + 8 * (r >> 2);
                float v0 = a0[r] * -131072.0f;
                int  s0 = (int)v0;
                int  key0 = (int)(((unsigned)s0 << 10)) + cbase + idx;
                k2[0] = imin(k2[0], imax(key0, k1[0]));
                k1[0] = imin(k1[0], key0);
                float v1 = a1[r] * -131072.0f;
                int  s1 = (int)v1;
                int  key1 = (int)(((unsigned)s1 << 10)) + cbase + idx;
                k2[1] = imin(k2[1], imax(key1, k1[1]));
                k1[1] = imin(k1[1], key1);
            }
        }
        __syncthreads();           // my reads done; staged chunk landed (vmcnt drain)
    }

    // merge complementary code-subsets (lane <-> lane^32), then lane's R = h row.
    int K1[2], K2[2];
#pragma unroll
    for (int R = 0; R < 2; ++R) {
        int o1 = __shfl_xor(k1[R], 32, 64);
        int o2 = __shfl_xor(k2[R], 32, 64);
        int mn = imin(k1[R], o1), mx = imax(k1[R], o1);
        K1[R] = mn;
        K2[R] = imin(imin(k2[R], o2), mx);
    }
    const int   bk1 = h ? K1[1] : K1[0];
    const int   bk2 = h ? K2[1] : K2[0];
    const float SA  = h ? sa[1] : sa[0];
    const int   row = rowbase + h * 32 + cl5;
    zout[row] = (float)(bk1 & 1023);
    const int Tint = (int)(65536.0f * (1.2e-4f * SA + 4e-4f));
    if ((bk2 - bk1) < ((Tint + 2) << 10)) {
        int id = atomicAdd(counter, 1);
        if (id < CAP) list[id] = row;
    }
}

// ---------------------------------------------------------------- exact rescore (bitwise ref)
__global__ __launch_bounds__(256) void rescore_kernel(
        const float* __restrict__ x, const float* __restrict__ cb,
        const float* __restrict__ csq, const int* __restrict__ counter,
        const int* __restrict__ list, float* __restrict__ zout) {
#pragma clang fp contract(off)
    const int wglobal = blockIdx.x * 4 + (threadIdx.x >> 6);
    const int lane    = threadIdx.x & 63;
    int cnt = *counter; if (cnt > CAP) cnt = CAP;

    for (int i = wglobal; i < cnt; i += 1024) {
        const int row = list[i];
        const float4* xr = reinterpret_cast<const float4*>(x + (size_t)row * DIM);
        float xv[64];
#pragma unroll
        for (int q = 0; q < 16; ++q) {
            float4 v = xr[q];
            xv[q * 4 + 0] = v.x; xv[q * 4 + 1] = v.y;
            xv[q * 4 + 2] = v.z; xv[q * 4 + 3] = v.w;
        }
        float r8[8];
#pragma unroll
        for (int g = 0; g < 8; ++g)
#pragma unroll
            for (int j = 0; j < 8; ++j) {
                float sq = xv[8 * g + j] * xv[8 * g + j];
                if (g == 0) r8[j] = sq; else r8[j] += sq;
            }
        float xsq = ((r8[0] + r8[1]) + (r8[2] + r8[3])) + ((r8[4] + r8[5]) + (r8[6] + r8[7]));

        float bm = INFINITY; int bi = 0;
        for (int cc = 0; cc < 16; ++cc) {
            int c = lane * 16 + cc;
            const float4* cr = reinterpret_cast<const float4*>(cb + (size_t)c * DIM);
            float dot = 0.0f;
#pragma unroll
            for (int q = 0; q < 16; ++q) {
                float4 v = cr[q];
                dot = __builtin_fmaf(v.x, xv[q * 4 + 0], dot);
                dot = __builtin_fmaf(v.y, xv[q * 4 + 1], dot);
                dot = __builtin_fmaf(v.z, xv[q * 4 + 2], dot);
                dot = __builtin_fmaf(v.w, xv[q * 4 + 3], dot);
            }
            float dist = (xsq - 2.0f * dot) + csq[c];
            if (dist < bm) { bm = dist; bi = c; }      // in-lane codes ascending
        }
#pragma unroll
        for (int m = 1; m <= 32; m <<= 1) {
            float ov = __shfl_xor(bm, m, 64);
            int   oi = __shfl_xor(bi, m, 64);
            if (ov < bm || (ov == bm && oi < bi)) { bm = ov; bi = oi; }
        }
        if (lane == 0) zout[row] = (float)bi;
    }
}

// ---------------------------------------------------------------- gather + ST out + losses
__global__ __launch_bounds__(256) void epilogue_kernel(
        const float* __restrict__ x, const float* __restrict__ cb,
        const float* __restrict__ zf, float* __restrict__ qout,
        double* __restrict__ partial) {
#pragma clang fp contract(off)
    const int gid = blockIdx.x * 256 + threadIdx.x;
    const int row = gid >> 2;
    const int d0  = (gid & 3) * 16;
    const float4* xr = reinterpret_cast<const float4*>(x + (size_t)row * DIM + d0);
    const int z = (int)zf[row];
    const float4* qr = reinterpret_cast<const float4*>(cb + (size_t)z * DIM + d0);
    float4* op = reinterpret_cast<float4*>(qout + (size_t)row * DIM + d0);

    double lsum = 0.0;
#pragma unroll
    for (int q = 0; q < 4; ++q) {
        float4 xv = xr[q];
        float4 qv = qr[q];
        float da = qv.x - xv.x, db = qv.y - xv.y, dc = qv.z - xv.z, dd = qv.w - xv.w;
        float4 o;
        o.x = xv.x + da; o.y = xv.y + db; o.z = xv.z + dc; o.w = xv.w + dd;
        op[q] = o;
        lsum += (double)(da * da) + (double)(db * db)
              + (double)(dc * dc) + (double)(dd * dd);
    }
#pragma unroll
    for (int s = 32; s >= 1; s >>= 1) lsum += __shfl_down(lsum, s, 64);
    __shared__ double wsum[4];
    const int lane = threadIdx.x & 63, wid = threadIdx.x >> 6;
    if (lane == 0) wsum[wid] = lsum;
    __syncthreads();
    if (threadIdx.x == 0)
        partial[blockIdx.x] = (wsum[0] + wsum[1]) + (wsum[2] + wsum[3]);
}

__global__ void finalize_kernel(const double* __restrict__ partial,
                                float* __restrict__ losses) {
    double s = 0.0;
    int lane = threadIdx.x;
    for (int i = lane; i < 4096; i += 64) s += partial[i];
#pragma unroll
    for (int sh = 32; sh >= 1; sh >>= 1) s += __shfl_down(s, sh, 64);
    if (lane == 0) {
        float v = (float)(s / 16777216.0);
        losses[0] = v;
        losses[1] = v;
    }
}

extern "C" void kernel_launch(void* const* d_in, const int* in_sizes, int n_in,
                              void* d_out, int out_size, void* d_ws, size_t ws_size,
                              hipStream_t stream) {
    const float* x  = (const float*)d_in[0];
    const float* cb = (const float*)d_in[1];
    float* out    = (float*)d_out;
    float* zout   = out;
    float* qout   = out + NROWS;
    float* losses = out + NROWS + (size_t)NROWS * DIM;

    float*          csq     = (float*)((char*)d_ws + CSQ_OFF);
    float*          cspre   = (float*)((char*)d_ws + CSPRE_OFF);
    unsigned short* csplit  = (unsigned short*)((char*)d_ws + CSPLIT_OFF);
    int*            counter = (int*)((char*)d_ws + CTR_OFF);
    int*            list    = (int*)((char*)d_ws + LIST_OFF);
    double*         partial = (double*)((char*)d_ws + PART_OFF);

    hipMemsetAsync(counter, 0, sizeof(int), stream);
    prep_kernel<<<16, 64, 0, stream>>>(cb, csq, cspre, csplit);
    vq_mfma_kernel<<<NROWS / 256, 256, 0, stream>>>(x, csplit, cspre, zout, counter, list);
    rescore_kernel<<<256, 256, 0, stream>>>(x, cb, csq, counter, list, zout);
    epilogue_kernel<<<(NROWS * 4) / 256, 256, 0, stream>>>(x, cb, zout, qout, partial);
    finalize_kernel<<<1, 64, 0, stream>>>(partial, losses);
}

// Round 5
// 372.405 us; speedup vs baseline: 1.4728x; 1.0136x over previous
//
#include <hip/hip_runtime.h>
#include <math.h>
#include <limits.h>

// VQVAE: N=262144, K=1024, D=64. Outputs flat fp32: Z[N], q_with_st[N*64], 2 losses.
// bf16-split MFMA distances with SWAPPED operands (D[code][row]; lane = x-row,
// regs = codes) so argmin state is per-lane scalar packed int keys.
// Ambiguous rows (top-2 gap <= T) exactly rescored with the bitwise
// reference-matching fp32 formula (verified absmax 0.0 in rounds 1/3/4).
// R5: rescore stages x in wave-local LDS (R4's xv[64] was demoted to scratch,
// VGPR_Count=52 -> 223us latency-bound thrash) + 2048-block grid.

static constexpr int NROWS = 262144;
static constexpr int KC    = 1024;
static constexpr int DIM   = 64;
static constexpr int CAP   = 65536;

// d_ws layout (bytes)
static constexpr size_t CSQ_OFF    = 0;          // 1024 f32
static constexpr size_t CSPRE_OFF  = 4096;       // 1024 f32 (= -csq/2)
static constexpr size_t CSPLIT_OFF = 8192;       // 16 chunks x 16 slots x 64 codes x 16B = 256 KB
static constexpr size_t CTR_OFF    = 270336;     // 1 int
static constexpr size_t LIST_OFF   = 270340;     // CAP ints
static constexpr size_t PART_OFF   = 532488;     // 4096 doubles

typedef __attribute__((ext_vector_type(8)))  short   short8;
typedef __attribute__((ext_vector_type(8)))  unsigned short ushort8;
typedef __attribute__((ext_vector_type(16))) float   f32x16;

static __device__ __forceinline__ unsigned short bf16rn(float f) {
    unsigned u = __float_as_uint(f);
    u += 0x7fffu + ((u >> 16) & 1u);      // round-nearest-even to bf16
    return (unsigned short)(u >> 16);
}
static __device__ __forceinline__ int imin(int a, int b) { return a < b ? a : b; }
static __device__ __forceinline__ int imax(int a, int b) { return a > b ? a : b; }

// ------------------------------------------------ prep: csq (exact), cs_pre, hi/lo split
// csplit ushort index = chk*8192 + slot*512 + c_l*8 + e ; chk=c>>6, c_l=c&63
// slot for hi of dim d: d>>3 ; for lo: 8+(d>>3) ; e = d&7.
__global__ __launch_bounds__(64) void prep_kernel(const float* __restrict__ cb,
                                                  float* __restrict__ csq,
                                                  float* __restrict__ cspre,
                                                  unsigned short* __restrict__ cs) {
#pragma clang fp contract(off)
    const int c = blockIdx.x * 64 + threadIdx.x;
    const float4* row = reinterpret_cast<const float4*>(cb + (size_t)c * DIM);
    float e[64];
#pragma unroll
    for (int q = 0; q < 16; ++q) {
        float4 v = row[q];
        e[q * 4 + 0] = v.x; e[q * 4 + 1] = v.y;
        e[q * 4 + 2] = v.z; e[q * 4 + 3] = v.w;
    }
    float r[8];
#pragma unroll
    for (int g = 0; g < 8; ++g)
#pragma unroll
        for (int j = 0; j < 8; ++j) {
            float sq = e[8 * g + j] * e[8 * g + j];     // rounded square (no fma)
            if (g == 0) r[j] = sq; else r[j] += sq;
        }
    float s = ((r[0] + r[1]) + (r[2] + r[3])) + ((r[4] + r[5]) + (r[6] + r[7]));
    csq[c]   = s;
    cspre[c] = -0.5f * s;                               // exact (x0.5)

    const int chk = c >> 6, c_l = c & 63;
    unsigned short* base = cs + (size_t)chk * 8192 + (size_t)c_l * 8;
#pragma unroll
    for (int g = 0; g < 8; ++g) {
        ushort8 hi, lo;
#pragma unroll
        for (int j = 0; j < 8; ++j) {
            float f = e[8 * g + j];
            unsigned short hb = bf16rn(f);
            float fh = __uint_as_float((unsigned)hb << 16);
            hi[j] = hb;
            lo[j] = bf16rn(f - fh);
        }
        *reinterpret_cast<ushort8*>(base + g * 512)       = hi;
        *reinterpret_cast<ushort8*>(base + (8 + g) * 512) = lo;
    }
}

// ------------------------------------------------ MFMA distance + packed-key argmin
// 256 thr = 4 waves; wave owns 64 rows (2 accs of 32). 16 chunks of 64 codes,
// double-buffered LDS staged via global_load_lds, 1 barrier/chunk.
#define STAGE(buf_, chk_) do {                                                          \
    const char* _s = (const char*)csplit + (size_t)(chk_) * 16384                       \
                     + (size_t)(w * 4) * 1024 + (size_t)lane * 16;                      \
    char* _d = (char*)(&bbuf[buf_][0]) + (size_t)(w * 4) * 1024;                        \
    _Pragma("unroll")                                                                   \
    for (int _it = 0; _it < 4; ++_it)                                                   \
        __builtin_amdgcn_global_load_lds(                                               \
            (const __attribute__((address_space(1))) unsigned int*)(_s + _it * 1024),   \
            (__attribute__((address_space(3))) unsigned int*)(_d + _it * 1024),         \
            16, 0, 0);                                                                  \
} while (0)

__global__ __launch_bounds__(256, 3) void vq_mfma_kernel(
        const float* __restrict__ x, const unsigned short* __restrict__ csplit,
        const float* __restrict__ cspre_g, float* __restrict__ zout,
        int* __restrict__ counter, int* __restrict__ list) {
    __shared__ unsigned short bbuf[2][8192];   // 2 x 16 KB
    __shared__ float cspre_s[1024];            // 4 KB

    const int tid  = threadIdx.x;
    const int w    = tid >> 6;
    const int lane = tid & 63;
    const int h    = lane >> 5;
    const int cl5  = lane & 31;
    const int rowbase = blockIdx.x * 256 + w * 64;

    STAGE(0, 0);                               // chunk 0 in flight

    {   // cs_pre -> LDS (256 thr x 4 floats)
        float4 v = reinterpret_cast<const float4*>(cspre_g)[tid];
        reinterpret_cast<float4*>(cspre_s)[tid] = v;
    }

    // x fragments (B-operand): col = lane&31 = row; k = h*8 + e per 16-step j.
    short8 xh[2][4], xl[2][4];
    float sa[2];
#pragma unroll
    for (int R = 0; R < 2; ++R) {
        const float* xrow = x + (size_t)(rowbase + R * 32 + cl5) * DIM;
        float s = 0.0f;
#pragma unroll
        for (int j = 0; j < 4; ++j) {
            float4 p0 = *reinterpret_cast<const float4*>(xrow + j * 16 + h * 8);
            float4 p1 = *reinterpret_cast<const float4*>(xrow + j * 16 + h * 8 + 4);
            float v[8] = {p0.x, p0.y, p0.z, p0.w, p1.x, p1.y, p1.z, p1.w};
#pragma unroll
            for (int e = 0; e < 8; ++e) {
                float f = v[e];
                s += fabsf(f);
                unsigned short hb = bf16rn(f);
                float fh = __uint_as_float((unsigned)hb << 16);
                xh[R][j][e] = (short)hb;
                xl[R][j][e] = (short)bf16rn(f - fh);
            }
        }
        s += __shfl_xor(s, 32, 64);            // complementary d-half, same row
        sa[R] = s;
    }
    __syncthreads();                           // chunk0 + cspre ready

    int k1[2] = {INT_MAX, INT_MAX};
    int k2[2] = {INT_MAX, INT_MAX};

    for (int chk = 0; chk < 16; ++chk) {
        const int cur = chk & 1;
        if (chk < 15) STAGE(cur ^ 1, chk + 1);
        const char* bb = (const char*)(&bbuf[cur][0]);
#pragma unroll
        for (int t = 0; t < 2; ++t) {
            const int cbase = chk * 64 + t * 32 + 4 * h;
            const float* cp = &cspre_s[cbase];             // broadcast reads
            float4 cg0 = *reinterpret_cast<const float4*>(cp);
            float4 cg1 = *reinterpret_cast<const float4*>(cp + 8);
            float4 cg2 = *reinterpret_cast<const float4*>(cp + 16);
            float4 cg3 = *reinterpret_cast<const float4*>(cp + 24);
            f32x16 a0;
            a0[0] = cg0.x; a0[1] = cg0.y; a0[2]  = cg0.z; a0[3]  = cg0.w;
            a0[4] = cg1.x; a0[5] = cg1.y; a0[6]  = cg1.z; a0[7]  = cg1.w;
            a0[8] = cg2.x; a0[9] = cg2.y; a0[10] = cg2.z; a0[11] = cg2.w;
            a0[12] = cg3.x; a0[13] = cg3.y; a0[14] = cg3.z; a0[15] = cg3.w;
            f32x16 a1 = a0;                                // acc init = -csq/2
            const char* bp = bb + (size_t)(t * 32 + cl5) * 16;
#pragma unroll
            for (int j = 0; j < 4; ++j) {                  // A-operand: codes
                short8 bch = *reinterpret_cast<const short8*>(bp + (2 * j + h) * 1024);
                short8 bcl = *reinterpret_cast<const short8*>(bp + (8 + 2 * j + h) * 1024);
                a0 = __builtin_amdgcn_mfma_f32_32x32x16_bf16(bch, xh[0][j], a0, 0, 0, 0);
                a1 = __builtin_amdgcn_mfma_f32_32x32x16_bf16(bch, xh[1][j], a1, 0, 0, 0);
                a0 = __builtin_amdgcn_mfma_f32_32x32x16_bf16(bch, xl[0][j], a0, 0, 0, 0);
                a1 = __builtin_amdgcn_mfma_f32_32x32x16_bf16(bch, xl[1][j], a1, 0, 0, 0);
                a0 = __builtin_amdgcn_mfma_f32_32x32x16_bf16(bcl, xh[0][j], a0, 0, 0, 0);
                a1 = __builtin_amdgcn_mfma_f32_32x32x16_bf16(bcl, xh[1][j], a1, 0, 0, 0);
            }
            // acc = dot - csq/2 ; key = (trunc(-131072*acc)<<10) | code
#pragma unroll
            for (int r = 0; r < 16; ++r) {
                const int idx = (r & 3) + 8 * (r >> 2);
                float v0 = a0[r] * -131072.0f;
                int  s0 = (int)v0;
                int  key0 = (int)(((unsigned)s0 << 10)) + cbase + idx;
                k2[0] = imin(k2[0], imax(key0, k1[0]));
                k1[0] = imin(k1[0], key0);
                float v1 = a1[r] * -131072.0f;
                int  s1 = (int)v1;
                int  key1 = (int)(((unsigned)s1 << 10)) + cbase + idx;
                k2[1] = imin(k2[1], imax(key1, k1[1]));
                k1[1] = imin(k1[1], key1);
            }
        }
        __syncthreads();           // my reads done; staged chunk landed (vmcnt drain)
    }

    // merge complementary code-subsets (lane <-> lane^32), then lane's R = h row.
    int K1[2], K2[2];
#pragma unroll
    for (int R = 0; R < 2; ++R) {
        int o1 = __shfl_xor(k1[R], 32, 64);
        int o2 = __shfl_xor(k2[R], 32, 64);
        int mn = imin(k1[R], o1), mx = imax(k1[R], o1);
        K1[R] = mn;
        K2[R] = imin(imin(k2[R], o2), mx);
    }
    const int   bk1 = h ? K1[1] : K1[0];
    const int   bk2 = h ? K2[1] : K2[0];
    const float SA  = h ? sa[1] : sa[0];
    const int   row = rowbase + h * 32 + cl5;
    zout[row] = (float)(bk1 & 1023);
    const int Tint = (int)(65536.0f * (1.2e-4f * SA + 4e-4f));
    if ((bk2 - bk1) < ((Tint + 2) << 10)) {
        int id = atomicAdd(counter, 1);
        if (id < CAP) list[id] = row;
    }
}

// ---------------------------------------------------------------- exact rescore (bitwise ref)
// R5: x row staged in wave-local LDS (broadcast reads) so no register array to
// spill; grid-strided over 2048 blocks. Math order bitwise-identical to R1.
__global__ __launch_bounds__(256) void rescore_kernel(
        const float* __restrict__ x, const float* __restrict__ cb,
        const float* __restrict__ csq, const int* __restrict__ counter,
        const int* __restrict__ list, float* __restrict__ zout) {
#pragma clang fp contract(off)
    __shared__ float xs[4][64];
    const int w    = threadIdx.x >> 6;
    const int lane = threadIdx.x & 63;
    const int wglobal = blockIdx.x * 4 + w;
    const int wstride = gridDim.x * 4;
    int cnt = *counter; if (cnt > CAP) cnt = CAP;

    for (int i = wglobal; i < cnt; i += wstride) {
        const int row = list[i];
        if (lane < 16) {
            float4 v = reinterpret_cast<const float4*>(x + (size_t)row * DIM)[lane];
            *reinterpret_cast<float4*>(&xs[w][lane * 4]) = v;
        }
        __builtin_amdgcn_wave_barrier();   // wave-local: keep write before reads
        // (compiler inserts lgkmcnt for the aliasing ds_read below)

        // x_sq: numpy pairwise structure, bitwise-same values from LDS
        float r8[8];
#pragma unroll
        for (int g = 0; g < 8; ++g)
#pragma unroll
            for (int j = 0; j < 8; ++j) {
                float xv = xs[w][8 * g + j];
                float sq = xv * xv;
                if (g == 0) r8[j] = sq; else r8[j] += sq;
            }
        float xsq = ((r8[0] + r8[1]) + (r8[2] + r8[3])) + ((r8[4] + r8[5]) + (r8[6] + r8[7]));

        float bm = INFINITY; int bi = 0;
        for (int cc = 0; cc < 16; ++cc) {
            int c = lane * 16 + cc;
            const float4* cr = reinterpret_cast<const float4*>(cb + (size_t)c * DIM);
            float dot = 0.0f;
#pragma unroll
            for (int q = 0; q < 16; ++q) {
                float4 v  = cr[q];
                float4 xv = *reinterpret_cast<const float4*>(&xs[w][q * 4]);
                dot = __builtin_fmaf(v.x, xv.x, dot);
                dot = __builtin_fmaf(v.y, xv.y, dot);
                dot = __builtin_fmaf(v.z, xv.z, dot);
                dot = __builtin_fmaf(v.w, xv.w, dot);
            }
            float dist = (xsq - 2.0f * dot) + csq[c];
            if (dist < bm) { bm = dist; bi = c; }      // in-lane codes ascending
        }
#pragma unroll
        for (int m = 1; m <= 32; m <<= 1) {
            float ov = __shfl_xor(bm, m, 64);
            int   oi = __shfl_xor(bi, m, 64);
            if (ov < bm || (ov == bm && oi < bi)) { bm = ov; bi = oi; }
        }
        if (lane == 0) zout[row] = (float)bi;
        __builtin_amdgcn_wave_barrier();   // don't overwrite xs before all lanes done
    }
}

// ---------------------------------------------------------------- gather + ST out + losses
__global__ __launch_bounds__(256) void epilogue_kernel(
        const float* __restrict__ x, const float* __restrict__ cb,
        const float* __restrict__ zf, float* __restrict__ qout,
        double* __restrict__ partial) {
#pragma clang fp contract(off)
    const int gid = blockIdx.x * 256 + threadIdx.x;
    const int row = gid >> 2;
    const int d0  = (gid & 3) * 16;
    const float4* xr = reinterpret_cast<const float4*>(x + (size_t)row * DIM + d0);
    const int z = (int)zf[row];
    const float4* qr = reinterpret_cast<const float4*>(cb + (size_t)z * DIM + d0);
    float4* op = reinterpret_cast<float4*>(qout + (size_t)row * DIM + d0);

    double lsum = 0.0;
#pragma unroll
    for (int q = 0; q < 4; ++q) {
        float4 xv = xr[q];
        float4 qv = qr[q];
        float da = qv.x - xv.x, db = qv.y - xv.y, dc = qv.z - xv.z, dd = qv.w - xv.w;
        float4 o;
        o.x = xv.x + da; o.y = xv.y + db; o.z = xv.z + dc; o.w = xv.w + dd;
        op[q] = o;
        lsum += (double)(da * da) + (double)(db * db)
              + (double)(dc * dc) + (double)(dd * dd);
    }
#pragma unroll
    for (int s = 32; s >= 1; s >>= 1) lsum += __shfl_down(lsum, s, 64);
    __shared__ double wsum[4];
    const int lane = threadIdx.x & 63, wid = threadIdx.x >> 6;
    if (lane == 0) wsum[wid] = lsum;
    __syncthreads();
    if (threadIdx.x == 0)
        partial[blockIdx.x] = (wsum[0] + wsum[1]) + (wsum[2] + wsum[3]);
}

__global__ void finalize_kernel(const double* __restrict__ partial,
                                float* __restrict__ losses) {
    double s = 0.0;
    int lane = threadIdx.x;
    for (int i = lane; i < 4096; i += 64) s += partial[i];
#pragma unroll
    for (int sh = 32; sh >= 1; sh >>= 1) s += __shfl_down(s, sh, 64);
    if (lane == 0) {
        float v = (float)(s / 16777216.0);
        losses[0] = v;
        losses[1] = v;
    }
}

extern "C" void kernel_launch(void* const* d_in, const int* in_sizes, int n_in,
                              void* d_out, int out_size, void* d_ws, size_t ws_size,
                              hipStream_t stream) {
    const float* x  = (const float*)d_in[0];
    const float* cb = (const float*)d_in[1];
    float* out    = (float*)d_out;
    float* zout   = out;
    float* qout   = out + NROWS;
    float* losses = out + NROWS + (size_t)NROWS * DIM;

    float*          csq     = (float*)((char*)d_ws + CSQ_OFF);
    float*          cspre   = (float*)((char*)d_ws + CSPRE_OFF);
    unsigned short* csplit  = (unsigned short*)((char*)d_ws + CSPLIT_OFF);
    int*            counter = (int*)((char*)d_ws + CTR_OFF);
    int*            list    = (int*)((char*)d_ws + LIST_OFF);
    double*         partial = (double*)((char*)d_ws + PART_OFF);

    hipMemsetAsync(counter, 0, sizeof(int), stream);
    prep_kernel<<<16, 64, 0, stream>>>(cb, csq, cspre, csplit);
    vq_mfma_kernel<<<NROWS / 256, 256, 0, stream>>>(x, csplit, cspre, zout, counter, list);
    rescore_kernel<<<2048, 256, 0, stream>>>(x, cb, csq, counter, list, zout);
    epilogue_kernel<<<(NROWS * 4) / 256, 256, 0, stream>>>(x, cb, zout, qout, partial);
    finalize_kernel<<<1, 64, 0, stream>>>(partial, losses);
}

// Round 6
// 253.544 us; speedup vs baseline: 2.1633x; 1.4688x over previous
//
#include <hip/hip_runtime.h>
#include <math.h>
#include <limits.h>

// VQVAE: N=262144, K=1024, D=64. Outputs flat fp32: Z[N], q_with_st[N*64], 2 losses.
// bf16-split MFMA distances with SWAPPED operands (D[code][row]; lane = x-row,
// regs = codes) so argmin state is per-lane scalar packed int keys.
// Ambiguous rows (top-2 gap <= T) exactly rescored with the bitwise
// reference-matching fp32 formula (verified absmax 0.0 in rounds 1/3/4/5).
// R6: rescore reads a TRANSPOSED codebook (cbT4[q][c], lane->code c=cc*64+lane)
// so all loads are wave-coalesced. R5's 221us was 64-way address divergence
// (16k transactions/row through the TA); math order is bit-identical.

static constexpr int NROWS = 262144;
static constexpr int KC    = 1024;
static constexpr int DIM   = 64;
static constexpr int CAP   = 65536;

// d_ws layout (bytes)
static constexpr size_t CSQ_OFF    = 0;          // 1024 f32
static constexpr size_t CSPRE_OFF  = 4096;       // 1024 f32 (= -csq/2)
static constexpr size_t CSPLIT_OFF = 8192;       // 16 chunks x 16 slots x 64 codes x 16B = 256 KB
static constexpr size_t CTR_OFF    = 270336;     // 1 int
static constexpr size_t LIST_OFF   = 270340;     // CAP ints
static constexpr size_t PART_OFF   = 532488;     // 4096 doubles

typedef __attribute__((ext_vector_type(8)))  short   short8;
typedef __attribute__((ext_vector_type(8)))  unsigned short ushort8;
typedef __attribute__((ext_vector_type(16))) float   f32x16;

static __device__ __forceinline__ unsigned short bf16rn(float f) {
    unsigned u = __float_as_uint(f);
    u += 0x7fffu + ((u >> 16) & 1u);      // round-nearest-even to bf16
    return (unsigned short)(u >> 16);
}
static __device__ __forceinline__ int imin(int a, int b) { return a < b ? a : b; }
static __device__ __forceinline__ int imax(int a, int b) { return a > b ? a : b; }

// ------------------------------------------------ prep: csq, cs_pre, hi/lo split, cbT
// csplit ushort index = chk*8192 + slot*512 + c_l*8 + e ; chk=c>>6, c_l=c&63
// slot for hi of dim d: d>>3 ; for lo: 8+(d>>3) ; e = d&7.
// cbT4: float4 cbT4[q*1024 + c] = cb[c][4q..4q+3]  (rescore coalesced reads)
__global__ __launch_bounds__(64) void prep_kernel(const float* __restrict__ cb,
                                                  float* __restrict__ csq,
                                                  float* __restrict__ cspre,
                                                  unsigned short* __restrict__ cs,
                                                  float4* __restrict__ cbt4) {
#pragma clang fp contract(off)
    const int c = blockIdx.x * 64 + threadIdx.x;
    const float4* row = reinterpret_cast<const float4*>(cb + (size_t)c * DIM);
    float e[64];
#pragma unroll
    for (int q = 0; q < 16; ++q) {
        float4 v = row[q];
        cbt4[q * 1024 + c] = v;                         // transposed copy
        e[q * 4 + 0] = v.x; e[q * 4 + 1] = v.y;
        e[q * 4 + 2] = v.z; e[q * 4 + 3] = v.w;
    }
    float r[8];
#pragma unroll
    for (int g = 0; g < 8; ++g)
#pragma unroll
        for (int j = 0; j < 8; ++j) {
            float sq = e[8 * g + j] * e[8 * g + j];     // rounded square (no fma)
            if (g == 0) r[j] = sq; else r[j] += sq;
        }
    float s = ((r[0] + r[1]) + (r[2] + r[3])) + ((r[4] + r[5]) + (r[6] + r[7]));
    csq[c]   = s;
    cspre[c] = -0.5f * s;                               // exact (x0.5)

    const int chk = c >> 6, c_l = c & 63;
    unsigned short* base = cs + (size_t)chk * 8192 + (size_t)c_l * 8;
#pragma unroll
    for (int g = 0; g < 8; ++g) {
        ushort8 hi, lo;
#pragma unroll
        for (int j = 0; j < 8; ++j) {
            float f = e[8 * g + j];
            unsigned short hb = bf16rn(f);
            float fh = __uint_as_float((unsigned)hb << 16);
            hi[j] = hb;
            lo[j] = bf16rn(f - fh);
        }
        *reinterpret_cast<ushort8*>(base + g * 512)       = hi;
        *reinterpret_cast<ushort8*>(base + (8 + g) * 512) = lo;
    }
}

// ------------------------------------------------ MFMA distance + packed-key argmin
// 256 thr = 4 waves; wave owns 64 rows (2 accs of 32). 16 chunks of 64 codes,
// double-buffered LDS staged via global_load_lds, 1 barrier/chunk.
#define STAGE(buf_, chk_) do {                                                          \
    const char* _s = (const char*)csplit + (size_t)(chk_) * 16384                       \
                     + (size_t)(w * 4) * 1024 + (size_t)lane * 16;                      \
    char* _d = (char*)(&bbuf[buf_][0]) + (size_t)(w * 4) * 1024;                        \
    _Pragma("unroll")                                                                   \
    for (int _it = 0; _it < 4; ++_it)                                                   \
        __builtin_amdgcn_global_load_lds(                                               \
            (const __attribute__((address_space(1))) unsigned int*)(_s + _it * 1024),   \
            (__attribute__((address_space(3))) unsigned int*)(_d + _it * 1024),         \
            16, 0, 0);                                                                  \
} while (0)

__global__ __launch_bounds__(256, 3) void vq_mfma_kernel(
        const float* __restrict__ x, const unsigned short* __restrict__ csplit,
        const float* __restrict__ cspre_g, float* __restrict__ zout,
        int* __restrict__ counter, int* __restrict__ list) {
    __shared__ unsigned short bbuf[2][8192];   // 2 x 16 KB
    __shared__ float cspre_s[1024];            // 4 KB

    const int tid  = threadIdx.x;
    const int w    = tid >> 6;
    const int lane = tid & 63;
    const int h    = lane >> 5;
    const int cl5  = lane & 31;
    const int rowbase = blockIdx.x * 256 + w * 64;

    STAGE(0, 0);                               // chunk 0 in flight

    {   // cs_pre -> LDS (256 thr x 4 floats)
        float4 v = reinterpret_cast<const float4*>(cspre_g)[tid];
        reinterpret_cast<float4*>(cspre_s)[tid] = v;
    }

    // x fragments (B-operand): col = lane&31 = row; k = h*8 + e per 16-step j.
    short8 xh[2][4], xl[2][4];
    float sa[2];
#pragma unroll
    for (int R = 0; R < 2; ++R) {
        const float* xrow = x + (size_t)(rowbase + R * 32 + cl5) * DIM;
        float s = 0.0f;
#pragma unroll
        for (int j = 0; j < 4; ++j) {
            float4 p0 = *reinterpret_cast<const float4*>(xrow + j * 16 + h * 8);
            float4 p1 = *reinterpret_cast<const float4*>(xrow + j * 16 + h * 8 + 4);
            float v[8] = {p0.x, p0.y, p0.z, p0.w, p1.x, p1.y, p1.z, p1.w};
#pragma unroll
            for (int e = 0; e < 8; ++e) {
                float f = v[e];
                s += fabsf(f);
                unsigned short hb = bf16rn(f);
                float fh = __uint_as_float((unsigned)hb << 16);
                xh[R][j][e] = (short)hb;
                xl[R][j][e] = (short)bf16rn(f - fh);
            }
        }
        s += __shfl_xor(s, 32, 64);            // complementary d-half, same row
        sa[R] = s;
    }
    __syncthreads();                           // chunk0 + cspre ready

    int k1[2] = {INT_MAX, INT_MAX};
    int k2[2] = {INT_MAX, INT_MAX};

    for (int chk = 0; chk < 16; ++chk) {
        const int cur = chk & 1;
        if (chk < 15) STAGE(cur ^ 1, chk + 1);
        const char* bb = (const char*)(&bbuf[cur][0]);
#pragma unroll
        for (int t = 0; t < 2; ++t) {
            const int cbase = chk * 64 + t * 32 + 4 * h;
            const float* cp = &cspre_s[cbase];             // broadcast reads
            float4 cg0 = *reinterpret_cast<const float4*>(cp);
            float4 cg1 = *reinterpret_cast<const float4*>(cp + 8);
            float4 cg2 = *reinterpret_cast<const float4*>(cp + 16);
            float4 cg3 = *reinterpret_cast<const float4*>(cp + 24);
            f32x16 a0;
            a0[0] = cg0.x; a0[1] = cg0.y; a0[2]  = cg0.z; a0[3]  = cg0.w;
            a0[4] = cg1.x; a0[5] = cg1.y; a0[6]  = cg1.z; a0[7]  = cg1.w;
            a0[8] = cg2.x; a0[9] = cg2.y; a0[10] = cg2.z; a0[11] = cg2.w;
            a0[12] = cg3.x; a0[13] = cg3.y; a0[14] = cg3.z; a0[15] = cg3.w;
            f32x16 a1 = a0;                                // acc init = -csq/2
            const char* bp = bb + (size_t)(t * 32 + cl5) * 16;
#pragma unroll
            for (int j = 0; j < 4; ++j) {                  // A-operand: codes
                short8 bch = *reinterpret_cast<const short8*>(bp + (2 * j + h) * 1024);
                short8 bcl = *reinterpret_cast<const short8*>(bp + (8 + 2 * j + h) * 1024);
                a0 = __builtin_amdgcn_mfma_f32_32x32x16_bf16(bch, xh[0][j], a0, 0, 0, 0);
                a1 = __builtin_amdgcn_mfma_f32_32x32x16_bf16(bch, xh[1][j], a1, 0, 0, 0);
                a0 = __builtin_amdgcn_mfma_f32_32x32x16_bf16(bch, xl[0][j], a0, 0, 0, 0);
                a1 = __builtin_amdgcn_mfma_f32_32x32x16_bf16(bch, xl[1][j], a1, 0, 0, 0);
                a0 = __builtin_amdgcn_mfma_f32_32x32x16_bf16(bcl, xh[0][j], a0, 0, 0, 0);
                a1 = __builtin_amdgcn_mfma_f32_32x32x16_bf16(bcl, xh[1][j], a1, 0, 0, 0);
            }
            // acc = dot - csq/2 ; key = (trunc(-131072*acc)<<10) | code
#pragma unroll
            for (int r = 0; r < 16; ++r) {
                const int idx = (r & 3) + 8 * (r >> 2);
                float v0 = a0[r] * -131072.0f;
                int  s0 = (int)v0;
                int  key0 = (int)(((unsigned)s0 << 10)) + cbase + idx;
                k2[0] = imin(k2[0], imax(key0, k1[0]));
                k1[0] = imin(k1[0], key0);
                float v1 = a1[r] * -131072.0f;
                int  s1 = (int)v1;
                int  key1 = (int)(((unsigned)s1 << 10)) + cbase + idx;
                k2[1] = imin(k2[1], imax(key1, k1[1]));
                k1[1] = imin(k1[1], key1);
            }
        }
        __syncthreads();           // my reads done; staged chunk landed (vmcnt drain)
    }

    // merge complementary code-subsets (lane <-> lane^32), then lane's R = h row.
    int K1[2], K2[2];
#pragma unroll
    for (int R = 0; R < 2; ++R) {
        int o1 = __shfl_xor(k1[R], 32, 64);
        int o2 = __shfl_xor(k2[R], 32, 64);
        int mn = imin(k1[R], o1), mx = imax(k1[R], o1);
        K1[R] = mn;
        K2[R] = imin(imin(k2[R], o2), mx);
    }
    const int   bk1 = h ? K1[1] : K1[0];
    const int   bk2 = h ? K2[1] : K2[0];
    const float SA  = h ? sa[1] : sa[0];
    const int   row = rowbase + h * 32 + cl5;
    zout[row] = (float)(bk1 & 1023);
    const int Tint = (int)(65536.0f * (1.2e-4f * SA + 4e-4f));
    if ((bk2 - bk1) < ((Tint + 2) << 10)) {
        int id = atomicAdd(counter, 1);
        if (id < CAP) list[id] = row;
    }
}

// ---------------------------------------------------------------- exact rescore (bitwise ref)
// R6: lane owns codes c = cc*64+lane; codebook read from cbT4 (transposed) so
// every load is wave-coalesced. FMA sequence d=0..63 identical to verified R1.
__global__ __launch_bounds__(256) void rescore_kernel(
        const float* __restrict__ x, const float4* __restrict__ cbt4,
        const float* __restrict__ csq, const int* __restrict__ counter,
        const int* __restrict__ list, float* __restrict__ zout) {
#pragma clang fp contract(off)
    __shared__ float xs[4][64];
    const int w    = threadIdx.x >> 6;
    const int lane = threadIdx.x & 63;
    const int wglobal = blockIdx.x * 4 + w;
    const int wstride = gridDim.x * 4;
    int cnt = *counter; if (cnt > CAP) cnt = CAP;

    for (int i = wglobal; i < cnt; i += wstride) {
        const int row = list[i];
        if (lane < 16) {
            float4 v = reinterpret_cast<const float4*>(x + (size_t)row * DIM)[lane];
            *reinterpret_cast<float4*>(&xs[w][lane * 4]) = v;
        }
        __builtin_amdgcn_wave_barrier();   // wave-local: keep write before reads

        // x_sq: numpy pairwise structure, bitwise-same values from LDS
        float r8[8];
#pragma unroll
        for (int g = 0; g < 8; ++g)
#pragma unroll
            for (int j = 0; j < 8; ++j) {
                float xv = xs[w][8 * g + j];
                float sq = xv * xv;
                if (g == 0) r8[j] = sq; else r8[j] += sq;
            }
        float xsq = ((r8[0] + r8[1]) + (r8[2] + r8[3])) + ((r8[4] + r8[5]) + (r8[6] + r8[7]));

        float bm = INFINITY; int bi = 0;
#pragma unroll 2
        for (int cc = 0; cc < 16; ++cc) {
            int c = cc * 64 + lane;                   // in-lane ascending
            float dot = 0.0f;
#pragma unroll
            for (int q = 0; q < 16; ++q) {
                float4 v  = cbt4[q * 1024 + c];       // coalesced: lanes contiguous
                float4 xv = *reinterpret_cast<const float4*>(&xs[w][q * 4]);
                dot = __builtin_fmaf(v.x, xv.x, dot);
                dot = __builtin_fmaf(v.y, xv.y, dot);
                dot = __builtin_fmaf(v.z, xv.z, dot);
                dot = __builtin_fmaf(v.w, xv.w, dot);
            }
            float dist = (xsq - 2.0f * dot) + csq[c];
            if (dist < bm) { bm = dist; bi = c; }
        }
#pragma unroll
        for (int m = 1; m <= 32; m <<= 1) {
            float ov = __shfl_xor(bm, m, 64);
            int   oi = __shfl_xor(bi, m, 64);
            if (ov < bm || (ov == bm && oi < bi)) { bm = ov; bi = oi; }
        }
        if (lane == 0) zout[row] = (float)bi;
        __builtin_amdgcn_wave_barrier();   // don't overwrite xs before all lanes done
    }
}

// ---------------------------------------------------------------- gather + ST out + losses
__global__ __launch_bounds__(256) void epilogue_kernel(
        const float* __restrict__ x, const float* __restrict__ cb,
        const float* __restrict__ zf, float* __restrict__ qout,
        double* __restrict__ partial) {
#pragma clang fp contract(off)
    const int gid = blockIdx.x * 256 + threadIdx.x;
    const int row = gid >> 2;
    const int d0  = (gid & 3) * 16;
    const float4* xr = reinterpret_cast<const float4*>(x + (size_t)row * DIM + d0);
    const int z = (int)zf[row];
    const float4* qr = reinterpret_cast<const float4*>(cb + (size_t)z * DIM + d0);
    float4* op = reinterpret_cast<float4*>(qout + (size_t)row * DIM + d0);

    double lsum = 0.0;
#pragma unroll
    for (int q = 0; q < 4; ++q) {
        float4 xv = xr[q];
        float4 qv = qr[q];
        float da = qv.x - xv.x, db = qv.y - xv.y, dc = qv.z - xv.z, dd = qv.w - xv.w;
        float4 o;
        o.x = xv.x + da; o.y = xv.y + db; o.z = xv.z + dc; o.w = xv.w + dd;
        op[q] = o;
        lsum += (double)(da * da) + (double)(db * db)
              + (double)(dc * dc) + (double)(dd * dd);
    }
#pragma unroll
    for (int s = 32; s >= 1; s >>= 1) lsum += __shfl_down(lsum, s, 64);
    __shared__ double wsum[4];
    const int lane = threadIdx.x & 63, wid = threadIdx.x >> 6;
    if (lane == 0) wsum[wid] = lsum;
    __syncthreads();
    if (threadIdx.x == 0)
        partial[blockIdx.x] = (wsum[0] + wsum[1]) + (wsum[2] + wsum[3]);
}

__global__ void finalize_kernel(const double* __restrict__ partial,
                                float* __restrict__ losses) {
    double s = 0.0;
    int lane = threadIdx.x;
    for (int i = lane; i < 4096; i += 64) s += partial[i];
#pragma unroll
    for (int sh = 32; sh >= 1; sh >>= 1) s += __shfl_down(s, sh, 64);
    if (lane == 0) {
        float v = (float)(s / 16777216.0);
        losses[0] = v;
        losses[1] = v;
    }
}

extern "C" void kernel_launch(void* const* d_in, const int* in_sizes, int n_in,
                              void* d_out, int out_size, void* d_ws, size_t ws_size,
                              hipStream_t stream) {
    const float* x  = (const float*)d_in[0];
    const float* cb = (const float*)d_in[1];
    float* out    = (float*)d_out;
    float* zout   = out;
    float* qout   = out + NROWS;
    float* losses = out + NROWS + (size_t)NROWS * DIM;

    float*          csq     = (float*)((char*)d_ws + CSQ_OFF);
    float*          cspre   = (float*)((char*)d_ws + CSPRE_OFF);
    unsigned short* csplit  = (unsigned short*)((char*)d_ws + CSPLIT_OFF);
    int*            counter = (int*)((char*)d_ws + CTR_OFF);
    int*            list    = (int*)((char*)d_ws + LIST_OFF);
    double*         partial = (double*)((char*)d_ws + PART_OFF);

    // cbT (256 KB) lives in the qout region of d_out: written by prep, read by
    // rescore, fully overwritten by epilogue afterwards. Zero d_ws growth.
    float4* cbt4 = (float4*)qout;

    hipMemsetAsync(counter, 0, sizeof(int), stream);
    prep_kernel<<<16, 64, 0, stream>>>(cb, csq, cspre, csplit, cbt4);
    vq_mfma_kernel<<<NROWS / 256, 256, 0, stream>>>(x, csplit, cspre, zout, counter, list);
    rescore_kernel<<<2048, 256, 0, stream>>>(x, cbt4, csq, counter, list, zout);
    epilogue_kernel<<<(NROWS * 4) / 256, 256, 0, stream>>>(x, cb, zout, qout, partial);
    finalize_kernel<<<1, 64, 0, stream>>>(partial, losses);
}